// Round 9
// baseline (257.403 us; speedup 1.0000x reference)
//
#include <hip/hip_runtime.h>
#include <hip/hip_cooperative_groups.h>
#include <math.h>

#define E_TOTAL 32768
#define NUM_NODES 4096
#define SCALE 0.70710678118654752f

namespace cg = cooperative_groups;

typedef __attribute__((ext_vector_type(8))) short bfrag;
typedef __attribute__((ext_vector_type(16))) float facc;

__device__ inline unsigned short f2bf(float f) {
  unsigned int u = __float_as_uint(f);
  unsigned int r = (u + 0x7FFFu + ((u >> 16) & 1u)) >> 16;
  return (unsigned short)r;
}
__device__ inline float bf2f(unsigned short s) {
  return __uint_as_float(((unsigned int)s) << 16);
}
__device__ inline void cvt8(const float* v, bfrag& hi, bfrag& lo) {
#pragma unroll
  for (int i = 0; i < 8; ++i) {
    unsigned short h = f2bf(v[i]);
    hi[i] = (short)h;
    lo[i] = (short)f2bf(v[i] - bf2f(h));
  }
}

// ---------------------------------------------------------------------------
// Single cooperative kernel: prep -> grid.sync -> z (R7 body) -> grid.sync ->
// segment softmax. Grid 512 (or 256 fallback) x 256 threads, co-resident by
// __launch_bounds__(256,2) (regs <=256/wave -> 2 blocks/CU; LDS 18.6 KB).
// fragWp layout per n-tile nt=c*6+w (4096 shorts = 8 KB):
//   [ks(4)][hl(2)][lane(64)][j(8)] bf16,
//   element = W_p[d][w*512 + c*32 + (lane&31)], d = ks*16 + (lane>>5)*8 + j
// ---------------------------------------------------------------------------
__global__ __launch_bounds__(256, 2) void mega_kernel(
    const float* __restrict__ x_q, const float* __restrict__ x_k,
    const float* __restrict__ emb, const int* __restrict__ index,
    const float* __restrict__ Wq, const float* __restrict__ Wp,
    unsigned short* __restrict__ fragWp, unsigned short* __restrict__ fragWq,
    int* __restrict__ offs, float* __restrict__ z, float* __restrict__ out)
{
  __shared__ unsigned short plds[4096];  // 8 KB (prep)
  __shared__ float xk_t[64][33];         // 8.4 KB, padded
  __shared__ float zred[4][32][4];       // 2 KB

  const int t = threadIdx.x;
  const int lane = t & 63, wv = t >> 6;
  const int pr = wv & 1, ch = wv >> 1;
  const int col = lane & 31, half = lane >> 5;

  // ============ Phase 1: prep (work items 0..230 across the grid) ============
  for (int b = blockIdx.x; b < 231; b += gridDim.x) {
    if (b < 96) {
      const int c = b / 6, w = b - c * 6;
      const int colbase = w * 512 + c * 32;
      const int cl = t & 31, dg = t >> 5;
#pragma unroll
      for (int i = 0; i < 8; ++i) {
        const int d = dg * 8 + i;
        const float v = Wp[(size_t)d * 3072 + colbase + cl];
        const unsigned short hi = f2bf(v);
        const unsigned short lo = f2bf(v - bf2f(hi));
        const int ks = d >> 4;
        const int ln = ((d >> 3) & 1) * 32 + cl;
        const int j = d & 7;
        plds[(ks * 2 + 0) * 512 + ln * 8 + j] = hi;
        plds[(ks * 2 + 1) * 512 + ln * 8 + j] = lo;
      }
      __syncthreads();
      unsigned short* dst = fragWp + (size_t)b * 4096;
      ((uint4*)dst)[t] = ((const uint4*)plds)[t];
      ((uint4*)dst)[t + 256] = ((const uint4*)plds)[t + 256];
      __syncthreads();
    } else if (b < 103) {
      const int slot = b - 96;
      const int w = (slot == 6) ? 5 : slot;
      const float sgn = (slot == 6) ? -1.f : 1.f;
      for (int tt = t; tt < 512; tt += 256) {
        const int ln = tt >> 3, j = tt & 7;
        const int o = ln & 31, c = (ln >> 5) * 8 + j;
        const float v = sgn * Wq[(size_t)(w * 16 + c) * 32 + o];
        const unsigned short hi = f2bf(v);
        const unsigned short lo = f2bf(v - bf2f(hi));
        fragWq[slot * 1024 + ln * 8 + j] = hi;
        fragWq[slot * 1024 + 512 + ln * 8 + j] = lo;
      }
    } else {
      const int tg = (b - 103) * 256 + t;
      if (tg < E_TOTAL) {
        const int cur = index[tg];
        const int prev = (tg == 0) ? -1 : index[tg - 1];
        for (int n = prev + 1; n <= cur; ++n) offs[n] = tg;
        if (tg == E_TOTAL - 1)
          for (int n = cur + 1; n <= NUM_NODES; ++n) offs[n] = E_TOTAL;
      }
    }
  }

  __threadfence();
  cg::this_grid().sync();

  // ============ Phase 2: z (R7 main body; 1024 edge-groups of 32) ============
  for (int g = blockIdx.x; g < 1024; g += gridDim.x) {
    const int eb = g * 32;
    const int e = eb + col;

    {  // stage x_k transposed
      const int er = t >> 3, dq = (t & 7) * 8;
      const float* src = x_k + (size_t)(eb + er) * 64 + dq;
      float4 v0 = *(const float4*)(src);
      float4 v1 = *(const float4*)(src + 4);
      xk_t[dq + 0][er] = v0.x; xk_t[dq + 1][er] = v0.y;
      xk_t[dq + 2][er] = v0.z; xk_t[dq + 3][er] = v0.w;
      xk_t[dq + 4][er] = v1.x; xk_t[dq + 5][er] = v1.y;
      xk_t[dq + 6][er] = v1.z; xk_t[dq + 7][er] = v1.w;
    }

    bfrag ebh[4], ebl[4];
#pragma unroll
    for (int ks = 0; ks < 4; ++ks) {
      float tmp[8];
      *(float4*)&tmp[0] = *(const float4*)(emb + (size_t)e * 64 + ks * 16 + half * 8);
      *(float4*)&tmp[4] = *(const float4*)(emb + (size_t)e * 64 + ks * 16 + half * 8 + 4);
      cvt8(tmp, ebh[ks], ebl[ks]);
    }

    facc ka0 = {0}, ka1 = {0}, ka2 = {0}, ka3 = {0};
    const unsigned short* fbase = fragWp + lane * 8;

    bfrag curh[4], curl[4], nxth[4], nxtl[4];
    {
      const unsigned short* gp = fbase + (size_t)(ch * 6 + pr) * 4096;
#pragma unroll
      for (int ks = 0; ks < 4; ++ks) {
        *(uint4*)&curh[ks] = *(const uint4*)(gp + ks * 1024);
        *(uint4*)&curl[ks] = *(const uint4*)(gp + ks * 1024 + 512);
      }
    }

    __syncthreads();  // xk_t ready

    float xkc0 = 0.f, xkc1 = 0.f, xkc2 = 0.f, xkc3 = 0.f;

#pragma unroll 6
    for (int idx = 0; idx < 24; ++idx) {
      const int j = idx % 3;
      {  // prefetch next tile: c = ch + 2*(nidx/3), w = pr + 2*(nidx%3)
        const int nidx = (idx < 23) ? idx + 1 : 23;
        const int nc = ch + 2 * (nidx / 3);
        const int nw = pr + 2 * (nidx - 3 * (nidx / 3));
        const unsigned short* gp = fbase + (size_t)(nc * 6 + nw) * 4096;
#pragma unroll
        for (int ks = 0; ks < 4; ++ks) {
          *(uint4*)&nxth[ks] = *(const uint4*)(gp + ks * 1024);
          *(uint4*)&nxtl[ks] = *(const uint4*)(gp + ks * 1024 + 512);
        }
      }
      if (j == 0) {
        const int c = ch + 2 * (idx / 3);
        xkc0 = xk_t[c][col];
        xkc1 = xk_t[16 + c][col];
        xkc2 = xk_t[32 + c][col];
        xkc3 = xk_t[48 + c][col];
      }
      facc cc0 = {0.f}, cc1 = {0.f}, cc2 = {0.f};
#pragma unroll
      for (int ks = 0; ks < 4; ++ks) {
        cc0 = __builtin_amdgcn_mfma_f32_32x32x16_bf16(curh[ks], ebh[ks], cc0, 0, 0, 0);
        cc1 = __builtin_amdgcn_mfma_f32_32x32x16_bf16(curh[ks], ebl[ks], cc1, 0, 0, 0);
        cc2 = __builtin_amdgcn_mfma_f32_32x32x16_bf16(curl[ks], ebh[ks], cc2, 0, 0, 0);
      }
      // so2: w0:x0->m0 w1:x0->m2 w2:x2->m0 w3:x2->m2 w4:x1->m1,x3->m3
      //      w5:x3->m1,-x1->m3.  This wave's w = pr + 2*j.
      if (j < 2) {
        const float xv = (j == 0) ? xkc0 : xkc2;
        if (pr == 0) {
#pragma unroll
          for (int r = 0; r < 16; ++r)
            ka0[r] = fmaf(xv, cc0[r] + cc1[r] + cc2[r], ka0[r]);
        } else {
#pragma unroll
          for (int r = 0; r < 16; ++r)
            ka2[r] = fmaf(xv, cc0[r] + cc1[r] + cc2[r], ka2[r]);
        }
      } else {
        if (pr == 0) {
#pragma unroll
          for (int r = 0; r < 16; ++r) {
            const float s = cc0[r] + cc1[r] + cc2[r];
            ka1[r] = fmaf(xkc1, s, ka1[r]);
            ka3[r] = fmaf(xkc3, s, ka3[r]);
          }
        } else {
#pragma unroll
          for (int r = 0; r < 16; ++r) {
            const float s = cc0[r] + cc1[r] + cc2[r];
            ka1[r] = fmaf(xkc3, s, ka1[r]);
            ka3[r] = fmaf(-xkc1, s, ka3[r]);
          }
        }
      }
#pragma unroll
      for (int ks = 0; ks < 4; ++ks) { curh[ks] = nxth[ks]; curl[ks] = nxtl[ks]; }
    }

    // q via MFMA (same C layout), partial z, 4-way LDS reduce
    bfrag xqh[4], xql[4];
#pragma unroll
    for (int a = 0; a < 4; ++a) {
      float tmp[8];
      *(float4*)&tmp[0] = *(const float4*)(x_q + (size_t)e * 64 + a * 16 + half * 8);
      *(float4*)&tmp[4] = *(const float4*)(x_q + (size_t)e * 64 + a * 16 + half * 8 + 4);
      cvt8(tmp, xqh[a], xql[a]);
    }
    float zp0 = 0.f, zp1 = 0.f, zp2 = 0.f, zp3 = 0.f;
    const int QA1[4] = {0, 1, 0, 3}, QS1[4] = {0, 4, 1, 4};
    const int QA2[4] = {2, 3, 2, 1}, QS2[4] = {2, 5, 3, 6};  // slot 6 = -Wq[5]
#pragma unroll
    for (int m = 0; m < 4; ++m) {
      facc qa = {0.f};
#pragma unroll
      for (int tm = 0; tm < 2; ++tm) {
        const int a = tm ? QA2[m] : QA1[m];
        const int sl = tm ? QS2[m] : QS1[m];
        bfrag wh, wl;
        *(uint4*)&wh = *(const uint4*)(fragWq + sl * 1024 + lane * 8);
        *(uint4*)&wl = *(const uint4*)(fragWq + sl * 1024 + 512 + lane * 8);
        qa = __builtin_amdgcn_mfma_f32_32x32x16_bf16(wh, xqh[a], qa, 0, 0, 0);
        qa = __builtin_amdgcn_mfma_f32_32x32x16_bf16(wh, xql[a], qa, 0, 0, 0);
        qa = __builtin_amdgcn_mfma_f32_32x32x16_bf16(wl, xqh[a], qa, 0, 0, 0);
      }
      const facc& km = (m == 0) ? ka0 : (m == 1) ? ka1 : (m == 2) ? ka2 : ka3;
#pragma unroll
      for (int r = 0; r < 16; ++r) {
        const float v = qa[r] * km[r];
        if (r < 4) zp0 += v;
        else if (r < 8) zp1 += v;
        else if (r < 12) zp2 += v;
        else zp3 += v;
      }
    }
    zp0 += __shfl_xor(zp0, 32);
    zp1 += __shfl_xor(zp1, 32);
    zp2 += __shfl_xor(zp2, 32);
    zp3 += __shfl_xor(zp3, 32);
    if (half == 0) {
      float4 v = {zp0, zp1, zp2, zp3};
      *(float4*)&zred[wv][col][0] = v;
    }
    __syncthreads();
    if (wv == 0 && half == 0) {
      float4 a = *(const float4*)&zred[0][col][0];
      float4 b = *(const float4*)&zred[1][col][0];
      float4 c4 = *(const float4*)&zred[2][col][0];
      float4 d4 = *(const float4*)&zred[3][col][0];
      float4 o = {(a.x + b.x + c4.x + d4.x) * SCALE,
                  (a.y + b.y + c4.y + d4.y) * SCALE,
                  (a.z + b.z + c4.z + d4.z) * SCALE,
                  (a.w + b.w + c4.w + d4.w) * SCALE};
      *(float4*)&z[(size_t)e * 4] = o;
    }
  }

  __threadfence();
  cg::this_grid().sync();

  // ============ Phase 3: segment softmax (1024 node-quads) ============
  for (int nb = blockIdx.x; nb < 1024; nb += gridDim.x) {
    const int node = nb * 4 + wv;
    const int start = offs[node], end = offs[node + 1];
    if (start < end) {  // wave-uniform
      const int h = lane & 3, eo = lane >> 2;
      float m = -INFINITY;
      for (int ee = start + eo; ee < end; ee += 16) m = fmaxf(m, z[(size_t)ee * 4 + h]);
#pragma unroll
      for (int s = 4; s < 64; s <<= 1) m = fmaxf(m, __shfl_xor(m, s));
      float sum = 0.f;
      for (int ee = start + eo; ee < end; ee += 16) sum += __expf(z[(size_t)ee * 4 + h] - m);
#pragma unroll
      for (int s = 4; s < 64; s <<= 1) sum += __shfl_xor(sum, s);
      const float inv = 1.f / sum;
      for (int ee = start + eo; ee < end; ee += 16)
        out[(size_t)ee * 4 + h] = __expf(z[(size_t)ee * 4 + h] - m) * inv;
    }
  }
}

extern "C" void kernel_launch(void* const* d_in, const int* in_sizes, int n_in,
                              void* d_out, int out_size, void* d_ws, size_t ws_size,
                              hipStream_t stream) {
  const float* x_q = (const float*)d_in[0];
  const float* x_k = (const float*)d_in[1];
  const float* emb = (const float*)d_in[2];
  const int* index = (const int*)d_in[3];
  const float* W_q = (const float*)d_in[4];
  const float* W_p = (const float*)d_in[5];
  float* out = (float*)d_out;

  char* ws = (char*)d_ws;
  float* z = (float*)ws;                                                     // 524288 B
  int* offs = (int*)(ws + 524288);                                           // 16388 B (pad 32 KB)
  unsigned short* fragWp = (unsigned short*)(ws + 524288 + 32768);           // 786432 B
  unsigned short* fragWq = (unsigned short*)(ws + 524288 + 32768 + 786432);  // 14336 B

  int maxb = 0;
  hipOccupancyMaxActiveBlocksPerMultiprocessor(&maxb, mega_kernel, 256, 0);
  const int grid = (maxb >= 2) ? 512 : 256;

  void* args[] = {(void*)&x_q, (void*)&x_k, (void*)&emb, (void*)&index,
                  (void*)&W_q, (void*)&W_p, (void*)&fragWp, (void*)&fragWq,
                  (void*)&offs, (void*)&z, (void*)&out};
  hipLaunchCooperativeKernel((void*)mega_kernel, dim3(grid), dim3(256),
                             args, 0, stream);
}